// Round 5
// baseline (53.640 us; speedup 1.0000x reference)
//
#include <hip/hip_runtime.h>
#include <math.h>

#define NSEG   30        // segments i = 0..29; segment entries 0..30
#define RECF   36        // floats per packed record (144 B, 16B-aligned, anti-conflict stride)
#define NREC   30
#define TABSZ  (RECF*NREC)   // 1080 floats = 4320 B
#define PPT    4

// Packed record r (float offsets within record, base = r*36):
//   0..5   Qa = Q_r      (x0,y0,x1,y1,x2,y2)
//   6..11  Qb = Q_{r+1}
//   12..20 Ta = T_r      (row-major 3x3)
//   21..29 Tb = T_{r+1}
//   30..35 pad
__global__ __launch_bounds__(256) void yuksel_fused(
    const float* __restrict__ x, const float* __restrict__ P,
    float* __restrict__ out, int N)
{
    __shared__ float lt[TABSZ];
    const int tid = threadIdx.x;

    // ---- per-block table build: 5 independent column recurrences, lanes 0..4 ----
    if (tid < 5) {
        const int  col = tid;
        const bool isQ = col < 2;
        const int  tc  = col - 2;

        float st0, st1, st2;
        if (isQ) {
            st0 = P[0*5+col]; st1 = P[1*5+col]; st2 = P[2*5+col];
        } else {
            float a0=P[0*5+2], b0=P[0*5+3], c0=P[0*5+4];
            float a1=P[1*5+2], b1=P[1*5+3], c1=P[1*5+4];
            float a2=P[2*5+2], b2=P[2*5+3], c2=P[2*5+4];
            st0 = (tc==0)? a0*a0+b0*b0 : (tc==1)? b0*(a0+c0) : b0*b0+c0*c0;
            st1 = (tc==0)? a1*a1+b1*b1 : (tc==1)? b1*(a1+c1) : b1*b1+c1*c1;
            st2 = (tc==0)? a2*a2+b2*b2 : (tc==1)? b2*(a2+c2) : b2*b2+c2*c2;
        }
        const int   stride = isQ ? 2 : 3;          // floats between rows
        const int   aoff   = isQ ? col       : (12 + tc);   // Qa/Ta column base
        const int   boff   = isQ ? (6 + col) : (21 + tc);   // Qb/Tb column base
        const float cA     = isQ ? 0.25f : 0.0625f;
        const float cB     = isQ ? 0.5f  : 0.25f;
        const float cC     = isQ ? 2.0f  : 4.0f;

        // write entry e's column into record e (as Qa/Ta) and record e-1 (as Qb/Tb)
        {
            // entry 0
            float* ra = lt + 0*RECF;
            ra[aoff+0*stride]=st0; ra[aoff+1*stride]=st1; ra[aoff+2*stride]=st2;
        }
        for (int i = 0; i < NSEG; ++i) {
            const int nr = i + 3;
            float nx;
            if (isQ) nx = P[nr*5+col];
            else {
                float a = P[nr*5+2], b = P[nr*5+3], c = P[nr*5+4];
                nx = (tc==0)? a*a+b*b : (tc==1)? b*(a+c) : b*b+c*c;
            }
            float n0 = (st0 + st2) * cA + st1 * cB;
            float n1 = cC * (st2 - (n0 + nx) * cA);
            st0 = n0; st1 = n1; st2 = nx;
            // entry e = i+1
            if (i + 1 < NREC) {           // as Qa/Ta of record i+1
                float* ra = lt + (i+1)*RECF;
                ra[aoff+0*stride]=st0; ra[aoff+1*stride]=st1; ra[aoff+2*stride]=st2;
            }
            {                              // as Qb/Tb of record i
                float* rb = lt + i*RECF;
                rb[boff+0*stride]=st0; rb[boff+1*stride]=st1; rb[boff+2*stride]=st2;
            }
        }
    }
    __syncthreads();

    const int gid = blockIdx.x * 256 + tid;
    const int j0  = gid * PPT;
    if (j0 >= N) return;

    float4 xv = *reinterpret_cast<const float4*>(x + j0);
    float xs[PPT] = { xv.x, xv.y, xv.z, xv.w };
    float mu[2*PPT], sg[3*PPT];

#pragma unroll
    for (int q = 0; q < PPT; ++q) {
        float u  = xs[q] * 30.0f;
        float fi = floorf(u);
        fi = fminf(fmaxf(fi, 0.0f), 29.0f);
        int   i  = (int)fi;
        float d  = (u - fi) * 0.5f;          // in [0, 0.5)
        float e  = d + 0.5f;

        float omd = 1.0f - d;
        float bc0 = omd * omd, bc1 = 2.0f * d * omd, bc2 = d * d;
        float ome = 1.0f - e;
        float bp0 = ome * ome, bp1 = 2.0f * e * ome, bp2 = e * e;

        float cpi = cospif(d);
        float cw  = cpi * cpi;
        float sw  = 1.0f - cw;
        float cw2 = cw * cw, sw2 = sw * sw;

        // 8x ds_read_b128 from one per-lane base + immediate offsets
        const float4* R = reinterpret_cast<const float4*>(lt + i * RECF);
        float4 r0 = R[0];   // Qa0 Qa1 Qa2 Qa3
        float4 r1 = R[1];   // Qa4 Qa5 Qb0 Qb1
        float4 r2 = R[2];   // Qb2 Qb3 Qb4 Qb5
        float4 r3 = R[3];   // Ta0..3
        float4 r4 = R[4];   // Ta4..7
        float4 r5 = R[5];   // Ta8 Tb0 Tb1 Tb2
        float4 r6 = R[6];   // Tb3..6
        float4 r7 = R[7];   // Tb7 Tb8 pad pad

        float fpx = bp0*r0.x + bp1*r0.z + bp2*r1.x;
        float fpy = bp0*r0.y + bp1*r0.w + bp2*r1.y;
        float fcx = bc0*r1.z + bc1*r2.y + bc2*r2.w;
        float fcy = bc0*r1.w + bc1*r2.z + bc2*r3.x*0.0f + bc2*r2.w*0.0f + bc2* r2.w*0.0f + bc2* r2.w*0.0f; // placeholder (fixed below)
        // NOTE: correct mapping spelled out explicitly:
        // Qb = {r1.z, r1.w, r2.x, r2.y, r2.z, r2.w}
        fcx = bc0*r1.z + bc1*r2.x + bc2*r2.z;
        fcy = bc0*r1.w + bc1*r2.y + bc2*r2.w;
        mu[2*q+0] = cw*fpx + sw*fcx;
        mu[2*q+1] = cw*fpy + sw*fcy;

        float a0 = bp0*bp0, a1 = bp1*bp1, a2 = bp2*bp2;
        float c0 = bc0*bc0, c1 = bc1*bc1, c2 = bc2*bc2;
        // Ta = {r3.x,r3.y,r3.z,r3.w, r4.x,r4.y,r4.z,r4.w, r5.x}  (row-major 3x3)
        float gp0 = a0*r3.x + a1*r3.w + a2*r4.z;
        float gp1 = a0*r3.y + a1*r4.x + a2*r4.w;
        float gp2 = a0*r3.z + a1*r4.y + a2*r5.x;
        // Tb = {r5.y,r5.z,r5.w, r6.x,r6.y,r6.z, r6.w,r7.x,r7.y}
        float gc0 = c0*r5.y + c1*r6.x + c2*r6.w;
        float gc1 = c0*r5.z + c1*r6.y + c2*r7.x;
        float gc2 = c0*r5.w + c1*r6.z + c2*r7.y;
        sg[3*q+0] = cw2*gp0 + sw2*gc0;
        sg[3*q+1] = cw2*gp1 + sw2*gc1;
        sg[3*q+2] = cw2*gp2 + sw2*gc2;
    }

    float4* muOut = reinterpret_cast<float4*>(out + 2*j0);
    muOut[0] = make_float4(mu[0], mu[1], mu[2], mu[3]);
    muOut[1] = make_float4(mu[4], mu[5], mu[6], mu[7]);
    float4* sgOut = reinterpret_cast<float4*>(out + (size_t)2*N + 3*j0);
    sgOut[0] = make_float4(sg[0], sg[1], sg[2],  sg[3]);
    sgOut[1] = make_float4(sg[4], sg[5], sg[6],  sg[7]);
    sgOut[2] = make_float4(sg[8], sg[9], sg[10], sg[11]);
}

extern "C" void kernel_launch(void* const* d_in, const int* in_sizes, int n_in,
                              void* d_out, int out_size, void* d_ws, size_t ws_size,
                              hipStream_t stream) {
    const float* x = (const float*)d_in[0];
    const float* P = (const float*)d_in[1];
    float* out = (float*)d_out;
    int N = in_sizes[0];

    const int threads = 256;
    const int per_block = threads * PPT;
    int blocks = (N + per_block - 1) / per_block;
    yuksel_fused<<<blocks, threads, 0, stream>>>(x, P, out, N);
}

// Round 6
// 30.327 us; speedup vs baseline: 1.7687x; 1.7687x over previous
//
#include <hip/hip_runtime.h>
#include <math.h>

#define QOFF 0           // Q table: 31 entries * 6 floats (rows stride 2)
#define TOFF 192         // T table: 31 entries * 9 floats (rows stride 3)
#define TABSZ 472
#define PPT 4
#define NBLK 2048

__global__ __launch_bounds__(256) void yuksel_fused(
    const float* __restrict__ x, const float* __restrict__ P,
    float* __restrict__ out, int N)
{
    __shared__ float lt[TABSZ];
    const int tid = threadIdx.x;

    // ---- fully parallel table build: 31 entries x 5 columns = 155 tasks ----
    // Closed form (M is nilpotent, M^2 = 0):
    //   entry_e (e>=2)  = ( p[e],  -p[e]/2 + 2 p[e+1] - p[e+2]/2,  p[e+2] )
    //   sigma entry_e   = ( s[e],  -s[e]/4 + 4 s[e+1] - s[e+2]/4,  s[e+2] )
    //   e=0: initial rows; e=1: one explicit recurrence step from initial.
    if (tid < 155) {
        const int e   = tid / 5;      // entry 0..30
        const int col = tid % 5;      // 0,1 = Q x,y ; 2,3,4 = sigma cols
        float v0, v1, v2;
        if (col < 2) {
            if (e == 0) {
                v0 = P[0*5+col]; v1 = P[1*5+col]; v2 = P[2*5+col];
            } else if (e == 1) {
                float p0=P[0*5+col], p1=P[1*5+col], p2=P[2*5+col], p3=P[3*5+col];
                v0 = (p0 + p2) * 0.25f + p1 * 0.5f;
                v1 = -p0*0.125f - p1*0.25f + p2*1.875f - p3*0.5f;
                v2 = p3;
            } else {
                float pe=P[e*5+col], pa=P[(e+1)*5+col], pb=P[(e+2)*5+col];
                v0 = pe;
                v1 = -pe*0.5f + 2.0f*pa - pb*0.5f;
                v2 = pb;
            }
            lt[QOFF + e*6 + col + 0] = v0;
            lt[QOFF + e*6 + col + 2] = v1;
            lt[QOFF + e*6 + col + 4] = v2;
        } else {
            const int tc = col - 2;
            auto sig = [&](int r) -> float {
                float a=P[r*5+2], b=P[r*5+3], c=P[r*5+4];
                return tc==0 ? a*a + b*b : (tc==1 ? b*(a+c) : b*b + c*c);
            };
            if (e == 0) {
                v0 = sig(0); v1 = sig(1); v2 = sig(2);
            } else if (e == 1) {
                float s0=sig(0), s1=sig(1), s2=sig(2), s3=sig(3);
                v0 = (s0 + s2) * 0.0625f + s1 * 0.25f;
                v1 = -s0*(1.0f/64.0f) - s1*0.0625f + s2*(255.0f/64.0f) - s3*0.25f;
                v2 = s3;
            } else {
                float se=sig(e), sa=sig(e+1), sb=sig(e+2);
                v0 = se;
                v1 = -se*0.25f + 4.0f*sa - sb*0.25f;
                v2 = sb;
            }
            lt[TOFF + e*9 + tc + 0] = v0;
            lt[TOFF + e*9 + tc + 3] = v1;
            lt[TOFF + e*9 + tc + 6] = v2;
        }
    }
    __syncthreads();

    const float* lQ = lt + QOFF;
    const float* lT = lt + TOFF;

    // ---- grid-stride over tiles; barrier-free steady loop ----
    const long long stride = (long long)gridDim.x * 256 * PPT;
    for (long long j0 = ((long long)blockIdx.x * 256 + tid) * PPT; j0 < N; j0 += stride) {
        float4 xv = *reinterpret_cast<const float4*>(x + j0);
        float xs[PPT] = { xv.x, xv.y, xv.z, xv.w };
        float mu[2*PPT], sg[3*PPT];

#pragma unroll
        for (int q = 0; q < PPT; ++q) {
            float u  = xs[q] * 30.0f;
            float fi = floorf(u);
            fi = fminf(fmaxf(fi, 0.0f), 29.0f);
            int   i  = (int)fi;
            float d  = (u - fi) * 0.5f;
            float e  = d + 0.5f;

            float omd = 1.0f - d;
            float bc0 = omd * omd, bc1 = 2.0f * d * omd, bc2 = d * d;
            float ome = 1.0f - e;
            float bp0 = ome * ome, bp1 = 2.0f * e * ome, bp2 = e * e;

            float cpi = cospif(d);
            float cw  = cpi * cpi;
            float sw  = 1.0f - cw;
            float cw2 = cw * cw, sw2 = sw * sw;

            const float* Qi = lQ + i * 6;    // entry i (6) then entry i+1 (6)
            const float* Ti = lT + i * 9;    // entry i (9) then entry i+1 (9)

            float fpx = bp0*Qi[0] + bp1*Qi[2] + bp2*Qi[4];
            float fpy = bp0*Qi[1] + bp1*Qi[3] + bp2*Qi[5];
            float fcx = bc0*Qi[6] + bc1*Qi[8] + bc2*Qi[10];
            float fcy = bc0*Qi[7] + bc1*Qi[9] + bc2*Qi[11];
            mu[2*q+0] = cw*fpx + sw*fcx;
            mu[2*q+1] = cw*fpy + sw*fcy;

            float a0 = bp0*bp0, a1 = bp1*bp1, a2 = bp2*bp2;
            float c0 = bc0*bc0, c1 = bc1*bc1, c2 = bc2*bc2;
            float gp0 = a0*Ti[0] + a1*Ti[3] + a2*Ti[6];
            float gp1 = a0*Ti[1] + a1*Ti[4] + a2*Ti[7];
            float gp2 = a0*Ti[2] + a1*Ti[5] + a2*Ti[8];
            float gc0 = c0*Ti[9]  + c1*Ti[12] + c2*Ti[15];
            float gc1 = c0*Ti[10] + c1*Ti[13] + c2*Ti[16];
            float gc2 = c0*Ti[11] + c1*Ti[14] + c2*Ti[17];
            sg[3*q+0] = cw2*gp0 + sw2*gc0;
            sg[3*q+1] = cw2*gp1 + sw2*gc1;
            sg[3*q+2] = cw2*gp2 + sw2*gc2;
        }

        float4* muOut = reinterpret_cast<float4*>(out + 2*j0);
        muOut[0] = make_float4(mu[0], mu[1], mu[2], mu[3]);
        muOut[1] = make_float4(mu[4], mu[5], mu[6], mu[7]);
        float4* sgOut = reinterpret_cast<float4*>(out + (size_t)2*N + 3*j0);
        sgOut[0] = make_float4(sg[0], sg[1], sg[2],  sg[3]);
        sgOut[1] = make_float4(sg[4], sg[5], sg[6],  sg[7]);
        sgOut[2] = make_float4(sg[8], sg[9], sg[10], sg[11]);
    }
}

extern "C" void kernel_launch(void* const* d_in, const int* in_sizes, int n_in,
                              void* d_out, int out_size, void* d_ws, size_t ws_size,
                              hipStream_t stream) {
    const float* x = (const float*)d_in[0];
    const float* P = (const float*)d_in[1];
    float* out = (float*)d_out;
    int N = in_sizes[0];

    const int threads = 256;
    const int per_block = threads * PPT;
    long long ntiles = (N + per_block - 1) / per_block;
    int blocks = (int)(ntiles < NBLK ? ntiles : NBLK);
    yuksel_fused<<<blocks, threads, 0, stream>>>(x, P, out, N);
}

// Round 7
// 26.283 us; speedup vs baseline: 2.0409x; 1.1539x over previous
//
#include <hip/hip_runtime.h>
#include <math.h>

#define NENT 33          // tap sequence entries 0..32
#define PPT 4
#define NBLK 2048

// LDS: 5 SoA arrays indexed by tap e: px, py, s0, s1, s2
__global__ __launch_bounds__(256) void yuksel_fused(
    const float* __restrict__ x, const float* __restrict__ P,
    float* __restrict__ out, int N)
{
    __shared__ float ltab[5][NENT];
    const int tid = threadIdx.x;

    // ---- fully parallel table build: 33 independent entries ----
    // ptilde[e] = p[e] except ptilde[1] = (p[0]+p[2])/4 + p[1]/2
    // stilde[e] = sig[e] except stilde[1] = (sig[0]+sig[2])/16 + sig[1]/4
    if (tid < NENT) {
        const int e = tid;
        float vals[5];
        if (e == 1) {
            float r0[5], r1[5], r2[5];
            for (int r = 0; r < 3; ++r) {
                float* dst = r==0 ? r0 : (r==1 ? r1 : r2);
                float a = P[r*5+2], b = P[r*5+3], c = P[r*5+4];
                dst[0] = P[r*5+0]; dst[1] = P[r*5+1];
                dst[2] = a*a + b*b; dst[3] = b*(a+c); dst[4] = b*b + c*c;
            }
            for (int k = 0; k < 2; ++k) vals[k] = (r0[k]+r2[k])*0.25f   + r1[k]*0.5f;
            for (int k = 2; k < 5; ++k) vals[k] = (r0[k]+r2[k])*0.0625f + r1[k]*0.25f;
        } else {
            float a = P[e*5+2], b = P[e*5+3], c = P[e*5+4];
            vals[0] = P[e*5+0]; vals[1] = P[e*5+1];
            vals[2] = a*a + b*b; vals[3] = b*(a+c); vals[4] = b*b + c*c;
        }
        for (int k = 0; k < 5; ++k) ltab[k][e] = vals[k];
    }
    __syncthreads();

    // ---- grid-stride eval: 4-tap filter per point ----
    const long long stride = (long long)gridDim.x * 256 * PPT;
    for (long long j0 = ((long long)blockIdx.x * 256 + tid) * PPT; j0 < N; j0 += stride) {
        float4 xv = *reinterpret_cast<const float4*>(x + j0);
        float xs[PPT] = { xv.x, xv.y, xv.z, xv.w };
        float mu[2*PPT], sg[3*PPT];

#pragma unroll
        for (int q = 0; q < PPT; ++q) {
            float u  = xs[q] * 30.0f;
            float fi = fminf(fmaxf(floorf(u), 0.0f), 29.0f);
            int   i  = (int)fi;
            float d  = (u - fi) * 0.5f;          // [0, 0.5)
            float e  = d + 0.5f;

            float omd = 1.0f - d, ome = 1.0f - e;
            float bc0 = omd*omd, bc1 = 2.0f*d*omd, bc2 = d*d;
            float bp0 = ome*ome, bp1 = 2.0f*e*ome, bp2 = e*e;

            // cw = cos^2(pi d) = (1 + cos(2 pi d))/2 ; v_cos_f32 arg is revolutions
            float cw  = 0.5f + 0.5f*__builtin_amdgcn_cosf(d);
            float sw  = 1.0f - cw;
            float cw2 = cw*cw, sw2 = sw*sw;

            // mu 4-tap weights
            float w0 = cw*(bp0 - 0.5f*bp1);
            float w1 = 2.0f*cw*bp1 + sw*(bc0 - 0.5f*bc1);
            float w2 = cw*(bp2 - 0.5f*bp1) + 2.0f*sw*bc1;
            float w3 = sw*(bc2 - 0.5f*bc1);
            // sg 4-tap weights (squared basis)
            float a0 = bp0*bp0, a1 = bp1*bp1, a2 = bp2*bp2;
            float c0 = bc0*bc0, c1 = bc1*bc1, c2 = bc2*bc2;
            float v0 = cw2*(a0 - 0.25f*a1);
            float v1 = 4.0f*cw2*a1 + sw2*(c0 - 0.25f*c1);
            float v2 = cw2*(a2 - 0.25f*a1) + 4.0f*sw2*c1;
            float v3 = sw2*(c2 - 0.25f*c1);

            // 20 scalar LDS reads, single vaddr (i*4) + immediate offsets
            float px0 = ltab[0][i],   px1 = ltab[0][i+1], px2 = ltab[0][i+2], px3 = ltab[0][i+3];
            float py0 = ltab[1][i],   py1 = ltab[1][i+1], py2 = ltab[1][i+2], py3 = ltab[1][i+3];
            float s00 = ltab[2][i],   s01 = ltab[2][i+1], s02 = ltab[2][i+2], s03 = ltab[2][i+3];
            float s10 = ltab[3][i],   s11 = ltab[3][i+1], s12 = ltab[3][i+2], s13 = ltab[3][i+3];
            float s20 = ltab[4][i],   s21 = ltab[4][i+1], s22 = ltab[4][i+2], s23 = ltab[4][i+3];

            mu[2*q+0] = w0*px0 + w1*px1 + w2*px2 + w3*px3;
            mu[2*q+1] = w0*py0 + w1*py1 + w2*py2 + w3*py3;
            sg[3*q+0] = v0*s00 + v1*s01 + v2*s02 + v3*s03;
            sg[3*q+1] = v0*s10 + v1*s11 + v2*s12 + v3*s13;
            sg[3*q+2] = v0*s20 + v1*s21 + v2*s22 + v3*s23;
        }

        float4* muOut = reinterpret_cast<float4*>(out + 2*j0);
        muOut[0] = make_float4(mu[0], mu[1], mu[2], mu[3]);
        muOut[1] = make_float4(mu[4], mu[5], mu[6], mu[7]);
        float4* sgOut = reinterpret_cast<float4*>(out + (size_t)2*N + 3*j0);
        sgOut[0] = make_float4(sg[0], sg[1], sg[2],  sg[3]);
        sgOut[1] = make_float4(sg[4], sg[5], sg[6],  sg[7]);
        sgOut[2] = make_float4(sg[8], sg[9], sg[10], sg[11]);
    }
}

extern "C" void kernel_launch(void* const* d_in, const int* in_sizes, int n_in,
                              void* d_out, int out_size, void* d_ws, size_t ws_size,
                              hipStream_t stream) {
    const float* x = (const float*)d_in[0];
    const float* P = (const float*)d_in[1];
    float* out = (float*)d_out;
    int N = in_sizes[0];

    const int threads = 256;
    const int per_block = threads * PPT;
    long long ntiles = (N + per_block - 1) / per_block;
    int blocks = (int)(ntiles < NBLK ? ntiles : NBLK);
    yuksel_fused<<<blocks, threads, 0, stream>>>(x, P, out, N);
}